// Round 1
// baseline (694.010 us; speedup 1.0000x reference)
//
#include <hip/hip_runtime.h>
#include <hip/hip_bf16.h>

// GCN encoder: 2x GCNConv (sym-norm, self-loops) + ReLU + row L2 normalize.
// N=50000, E=800000, IN=128, HID=256, OUT=256. All fp32.

#define NNODE 50000
#define FDIM 256

// ---- CSR build ----------------------------------------------------------
__global__ void count_kernel(const int* __restrict__ ei, int* __restrict__ counts, int E) {
    int e = blockIdx.x * blockDim.x + threadIdx.x;
    if (e < E) {
        int d = ei[E + e];  // edge_index[1][e] = dst
        atomicAdd(&counts[d], 1);
    }
}

__global__ __launch_bounds__(1024) void scan_kernel(const int* __restrict__ counts,
                                                    int* __restrict__ row_ptr,
                                                    int* __restrict__ cursor, int n) {
    __shared__ int wsum[16];
    __shared__ int s_carry;
    int t = threadIdx.x, lane = t & 63, wid = t >> 6;
    if (t == 0) s_carry = 0;
    __syncthreads();
    for (int base = 0; base < n; base += 1024) {
        int i = base + t;
        int v = (i < n) ? counts[i] : 0;
        int incl = v;
#pragma unroll
        for (int off = 1; off < 64; off <<= 1) {
            int u = __shfl_up(incl, off, 64);
            if (lane >= off) incl += u;
        }
        if (lane == 63) wsum[wid] = incl;
        __syncthreads();
        if (wid == 0) {
            int w = (lane < 16) ? wsum[lane] : 0;
#pragma unroll
            for (int off = 1; off < 16; off <<= 1) {
                int u = __shfl_up(w, off, 64);
                if (lane >= off) w += u;
            }
            if (lane < 16) wsum[lane] = w;
        }
        __syncthreads();
        int waveoff = (wid > 0) ? wsum[wid - 1] : 0;
        int carry = s_carry;
        int ex = carry + waveoff + incl - v;
        if (i < n) { row_ptr[i] = ex; cursor[i] = ex; }
        __syncthreads();
        if (t == 1023) s_carry = carry + waveoff + incl;
        __syncthreads();
    }
    if (threadIdx.x == 0) row_ptr[n] = s_carry;
}

__global__ void dinv_kernel(const int* __restrict__ counts, float* __restrict__ dinv, int n) {
    int i = blockIdx.x * blockDim.x + threadIdx.x;
    if (i < n) dinv[i] = rsqrtf((float)(counts[i] + 1));  // +1 self-loop
}

__global__ void fill_kernel(const int* __restrict__ ei, const float* __restrict__ dinv,
                            int* __restrict__ cursor, int* __restrict__ col,
                            float* __restrict__ normv, int E) {
    int e = blockIdx.x * blockDim.x + threadIdx.x;
    if (e < E) {
        int s = ei[e];
        int d = ei[E + e];
        int pos = atomicAdd(&cursor[d], 1);
        col[pos] = s;
        normv[pos] = dinv[s] * dinv[d];
    }
}

// ---- GEMM: H[n,256] = X[n,K] @ W[K,256] ---------------------------------
// 256 threads/block, 16 rows/block. Thread t owns output column t.
template <int K>
__global__ __launch_bounds__(256) void gemm_rows16(const float* __restrict__ X,
                                                   const float* __restrict__ W,
                                                   float* __restrict__ H, int n) {
    __shared__ float xs[16][K];
    int row0 = blockIdx.x * 16;
    int t = threadIdx.x;
    for (int idx = t; idx < 16 * K; idx += 256) {
        int r = idx / K, k = idx % K;
        int row = row0 + r;
        xs[r][k] = (row < n) ? X[(size_t)row * K + k] : 0.f;
    }
    __syncthreads();
    float acc[16];
#pragma unroll
    for (int r = 0; r < 16; ++r) acc[r] = 0.f;
    for (int k = 0; k < K; ++k) {
        float w = W[(size_t)k * 256 + t];
#pragma unroll
        for (int r = 0; r < 16; ++r) acc[r] = fmaf(xs[r][k], w, acc[r]);
    }
#pragma unroll
    for (int r = 0; r < 16; ++r) {
        int row = row0 + r;
        if (row < n) H[(size_t)row * 256 + t] = acc[r];
    }
}

// ---- Aggregation: out[i] = relu(b + h[i]*dinv[i]^2 + sum h[src]*norm) ---
__global__ __launch_bounds__(256) void agg_relu_kernel(const float* __restrict__ h,
                                                       const int* __restrict__ row_ptr,
                                                       const int* __restrict__ col,
                                                       const float* __restrict__ normv,
                                                       const float* __restrict__ dinv,
                                                       const float* __restrict__ bias,
                                                       float* __restrict__ out, int n) {
    int i = blockIdx.x;
    int t = threadIdx.x;
    float di = dinv[i];
    float acc = bias[t] + h[(size_t)i * FDIM + t] * di * di;
    int beg = row_ptr[i], end = row_ptr[i + 1];
    for (int e = beg; e < end; ++e) {
        int s = col[e];
        float nm = normv[e];
        acc = fmaf(h[(size_t)s * FDIM + t], nm, acc);
    }
    out[(size_t)i * FDIM + t] = fmaxf(acc, 0.f);
}

// ---- Aggregation + bias + row L2 normalize (final layer) ----------------
__global__ __launch_bounds__(256) void agg_norm_kernel(const float* __restrict__ h,
                                                       const int* __restrict__ row_ptr,
                                                       const int* __restrict__ col,
                                                       const float* __restrict__ normv,
                                                       const float* __restrict__ dinv,
                                                       const float* __restrict__ bias,
                                                       float* __restrict__ out, int n) {
    __shared__ float red[4];
    int i = blockIdx.x;
    int t = threadIdx.x;
    int lane = t & 63, wid = t >> 6;
    float di = dinv[i];
    float acc = bias[t] + h[(size_t)i * FDIM + t] * di * di;
    int beg = row_ptr[i], end = row_ptr[i + 1];
    for (int e = beg; e < end; ++e) {
        int s = col[e];
        float nm = normv[e];
        acc = fmaf(h[(size_t)s * FDIM + t], nm, acc);
    }
    float ss = acc * acc;
#pragma unroll
    for (int off = 32; off >= 1; off >>= 1) ss += __shfl_xor(ss, off, 64);
    if (lane == 0) red[wid] = ss;
    __syncthreads();
    float tot = red[0] + red[1] + red[2] + red[3];
    float nrm = fmaxf(sqrtf(tot), 1e-12f);
    out[(size_t)i * FDIM + t] = acc / nrm;
}

extern "C" void kernel_launch(void* const* d_in, const int* in_sizes, int n_in,
                              void* d_out, int out_size, void* d_ws, size_t ws_size,
                              hipStream_t stream) {
    const float* x  = (const float*)d_in[0];
    const int*   ei = (const int*)d_in[1];
    const float* W1 = (const float*)d_in[2];
    const float* b1 = (const float*)d_in[3];
    const float* W2 = (const float*)d_in[4];
    const float* b2 = (const float*)d_in[5];
    float* out = (float*)d_out;

    const int N = NNODE;
    const int E = in_sizes[1] / 2;

    char* ws = (char*)d_ws;
    size_t off = 0;
    auto alloc = [&](size_t bytes) -> void* {
        void* p = ws + off;
        off = (off + bytes + 255) & ~(size_t)255;
        return p;
    };
    float* A      = (float*)alloc((size_t)N * FDIM * 4);  // h1, then h2
    float* B      = (float*)alloc((size_t)N * FDIM * 4);  // relu(gcn1)
    int*   counts = (int*)alloc((size_t)N * 4);
    int*   rowp   = (int*)alloc((size_t)(N + 1) * 4);
    int*   cursor = (int*)alloc((size_t)N * 4);
    float* dinv   = (float*)alloc((size_t)N * 4);
    int*   col    = (int*)alloc((size_t)E * 4);
    float* normv  = (float*)alloc((size_t)E * 4);

    hipMemsetAsync(counts, 0, (size_t)N * 4, stream);
    count_kernel<<<(E + 255) / 256, 256, 0, stream>>>(ei, counts, E);
    scan_kernel<<<1, 1024, 0, stream>>>(counts, rowp, cursor, N);
    dinv_kernel<<<(N + 255) / 256, 256, 0, stream>>>(counts, dinv, N);
    fill_kernel<<<(E + 255) / 256, 256, 0, stream>>>(ei, dinv, cursor, col, normv, E);

    gemm_rows16<128><<<(N + 15) / 16, 256, 0, stream>>>(x, W1, A, N);
    agg_relu_kernel<<<N, 256, 0, stream>>>(A, rowp, col, normv, dinv, b1, B, N);
    gemm_rows16<256><<<(N + 15) / 16, 256, 0, stream>>>(B, W2, A, N);
    agg_norm_kernel<<<N, 256, 0, stream>>>(A, rowp, col, normv, dinv, b2, out, N);
}

// Round 2
// 401.578 us; speedup vs baseline: 1.7282x; 1.7282x over previous
//
#include <hip/hip_runtime.h>
#include <hip/hip_bf16.h>

// GCN encoder: 2x GCNConv (sym-norm, self-loops) + ReLU + row L2 normalize.
// N=50000, E=800000, IN=128, HID=256, OUT=256.
// fp32 GEMMs, bf16 gather payload, fp32 accumulation.

#define NNODE 50000
#define FDIM 256
#define SCAN_CHUNK 2048

__device__ __forceinline__ float bf2f(unsigned short u) {
    union { unsigned int i; float f; } c;
    c.i = ((unsigned int)u) << 16;
    return c.f;
}
__device__ __forceinline__ unsigned short f2bf(float f) {
    __hip_bfloat16 h = __float2bfloat16(f);  // RTN
    return *reinterpret_cast<unsigned short*>(&h);
}

// ---- CSR build ----------------------------------------------------------
__global__ void count_kernel(const int* __restrict__ ei, int* __restrict__ counts, int E) {
    int e = blockIdx.x * blockDim.x + threadIdx.x;
    if (e < E) atomicAdd(&counts[ei[E + e]], 1);
}

// Hierarchical scan: part1 per-block sums, part2 single-wave scan of block
// sums (+ writes row_ptr[n]), part3 per-block exclusive scan with offset.
__global__ __launch_bounds__(256) void scan_part1(const int* __restrict__ counts,
                                                  int* __restrict__ bsum, int n) {
    __shared__ int ws[4];
    int b = blockIdx.x, t = threadIdx.x;
    int base = b * SCAN_CHUNK + t * 8;
    int s = 0;
#pragma unroll
    for (int j = 0; j < 8; ++j) {
        int i = base + j;
        if (i < n) s += counts[i];
    }
#pragma unroll
    for (int off = 32; off >= 1; off >>= 1) s += __shfl_xor(s, off, 64);
    if ((t & 63) == 0) ws[t >> 6] = s;
    __syncthreads();
    if (t == 0) bsum[b] = ws[0] + ws[1] + ws[2] + ws[3];
}

__global__ void scan_part2(const int* __restrict__ bsum, int* __restrict__ boff,
                           int* __restrict__ row_ptr, int nb, int n) {
    int l = threadIdx.x;
    int v = (l < nb) ? bsum[l] : 0;
    int incl = v;
#pragma unroll
    for (int off = 1; off < 64; off <<= 1) {
        int u = __shfl_up(incl, off, 64);
        if (l >= off) incl += u;
    }
    if (l < nb) boff[l] = incl - v;
    if (l == nb - 1) row_ptr[n] = incl;  // total == E
}

__global__ __launch_bounds__(256) void scan_part3(const int* __restrict__ counts,
                                                  const int* __restrict__ boff,
                                                  int* __restrict__ row_ptr,
                                                  int* __restrict__ cursor, int n) {
    __shared__ int ws[4];
    int b = blockIdx.x, t = threadIdx.x, lane = t & 63, wid = t >> 6;
    int base = b * SCAN_CHUNK + t * 8;
    int v[8];
    int s = 0;
#pragma unroll
    for (int j = 0; j < 8; ++j) {
        int i = base + j;
        v[j] = (i < n) ? counts[i] : 0;
        s += v[j];
    }
    int incl = s;
#pragma unroll
    for (int off = 1; off < 64; off <<= 1) {
        int u = __shfl_up(incl, off, 64);
        if (lane >= off) incl += u;
    }
    if (lane == 63) ws[wid] = incl;
    __syncthreads();
    int woff = 0;
    for (int u = 0; u < wid; ++u) woff += ws[u];
    int ex = boff[b] + woff + incl - s;
#pragma unroll
    for (int j = 0; j < 8; ++j) {
        int i = base + j;
        if (i < n) { row_ptr[i] = ex; cursor[i] = ex; }
        ex += v[j];
    }
}

__global__ void dinv_kernel(const int* __restrict__ counts, float* __restrict__ dinv, int n) {
    int i = blockIdx.x * blockDim.x + threadIdx.x;
    if (i < n) dinv[i] = rsqrtf((float)(counts[i] + 1));  // +1 self-loop
}

__global__ void fill_kernel(const int* __restrict__ ei, const float* __restrict__ dinv,
                            int* __restrict__ cursor, int2* __restrict__ edata, int E) {
    int e = blockIdx.x * blockDim.x + threadIdx.x;
    if (e < E) {
        int s = ei[e];
        int d = ei[E + e];
        int pos = atomicAdd(&cursor[d], 1);
        float nm = dinv[s] * dinv[d];
        edata[pos] = make_int2(s, __float_as_int(nm));
    }
}

// ---- GEMM: Hbf[n,256] = bf16(X[n,K] @ W[K,256]) -------------------------
// 16 rows/block, 256 threads; thread t owns output column t.
// LDS staged transposed (xs[k][r]) so the inner loop reads float4 broadcasts.
template <int K>
__global__ __launch_bounds__(256) void gemm16(const float* __restrict__ X,
                                              const float* __restrict__ W,
                                              unsigned short* __restrict__ H, int n) {
    __shared__ float xs[K][16];
    int row0 = blockIdx.x * 16;
    int t = threadIdx.x;
    for (int idx = t; idx < 16 * K; idx += 256) {
        int r = idx & 15;          // row within tile
        int k = idx >> 4;          // reduction index
        int row = row0 + r;
        xs[k][r] = (row < n) ? X[(size_t)row * K + k] : 0.f;  // LDS write = linear in idx
    }
    __syncthreads();
    float acc[16];
#pragma unroll
    for (int r = 0; r < 16; ++r) acc[r] = 0.f;
    for (int k = 0; k < K; ++k) {
        float wv = W[(size_t)k * 256 + t];
        float4 x0 = *reinterpret_cast<const float4*>(&xs[k][0]);
        float4 x1 = *reinterpret_cast<const float4*>(&xs[k][4]);
        float4 x2 = *reinterpret_cast<const float4*>(&xs[k][8]);
        float4 x3 = *reinterpret_cast<const float4*>(&xs[k][12]);
        acc[0]  = fmaf(x0.x, wv, acc[0]);
        acc[1]  = fmaf(x0.y, wv, acc[1]);
        acc[2]  = fmaf(x0.z, wv, acc[2]);
        acc[3]  = fmaf(x0.w, wv, acc[3]);
        acc[4]  = fmaf(x1.x, wv, acc[4]);
        acc[5]  = fmaf(x1.y, wv, acc[5]);
        acc[6]  = fmaf(x1.z, wv, acc[6]);
        acc[7]  = fmaf(x1.w, wv, acc[7]);
        acc[8]  = fmaf(x2.x, wv, acc[8]);
        acc[9]  = fmaf(x2.y, wv, acc[9]);
        acc[10] = fmaf(x2.z, wv, acc[10]);
        acc[11] = fmaf(x2.w, wv, acc[11]);
        acc[12] = fmaf(x3.x, wv, acc[12]);
        acc[13] = fmaf(x3.y, wv, acc[13]);
        acc[14] = fmaf(x3.z, wv, acc[14]);
        acc[15] = fmaf(x3.w, wv, acc[15]);
    }
#pragma unroll
    for (int r = 0; r < 16; ++r) {
        int row = row0 + r;
        if (row < n) H[(size_t)row * 256 + t] = f2bf(acc[r]);
    }
}

// ---- Aggregation, wave-per-node. Lane l owns features [4l, 4l+4). -------
// acc = bias + h[i]*dinv[i]^2 + sum_{e} h[src_e]*norm_e   (bf16 rows, fp32 acc)
__device__ __forceinline__ void agg_core(const unsigned short* __restrict__ hb,
                                         const int* __restrict__ rowp,
                                         const int2* __restrict__ edata,
                                         const float* __restrict__ dinv,
                                         const float* __restrict__ bias,
                                         int node, int lane,
                                         float& a0, float& a1, float& a2, float& a3) {
    float di = dinv[node];
    float d2 = di * di;
    ushort4 sv = *(reinterpret_cast<const ushort4*>(hb + (size_t)node * FDIM) + lane);
    float4 bv = *(reinterpret_cast<const float4*>(bias) + lane);
    a0 = fmaf(bf2f(sv.x), d2, bv.x);
    a1 = fmaf(bf2f(sv.y), d2, bv.y);
    a2 = fmaf(bf2f(sv.z), d2, bv.z);
    a3 = fmaf(bf2f(sv.w), d2, bv.w);
    int beg = rowp[node], end = rowp[node + 1];
#pragma unroll 4
    for (int e = beg; e < end; ++e) {
        int2 ed = edata[e];
        float nm = __int_as_float(ed.y);
        ushort4 v = *(reinterpret_cast<const ushort4*>(hb + (size_t)ed.x * FDIM) + lane);
        a0 = fmaf(bf2f(v.x), nm, a0);
        a1 = fmaf(bf2f(v.y), nm, a1);
        a2 = fmaf(bf2f(v.z), nm, a2);
        a3 = fmaf(bf2f(v.w), nm, a3);
    }
}

__global__ __launch_bounds__(256) void agg_relu_kernel(const unsigned short* __restrict__ hb,
                                                       const int* __restrict__ rowp,
                                                       const int2* __restrict__ edata,
                                                       const float* __restrict__ dinv,
                                                       const float* __restrict__ bias,
                                                       float* __restrict__ outB, int n) {
    int node = (blockIdx.x * blockDim.x + threadIdx.x) >> 6;
    int lane = threadIdx.x & 63;
    if (node >= n) return;
    float a0, a1, a2, a3;
    agg_core(hb, rowp, edata, dinv, bias, node, lane, a0, a1, a2, a3);
    float4 o = make_float4(fmaxf(a0, 0.f), fmaxf(a1, 0.f), fmaxf(a2, 0.f), fmaxf(a3, 0.f));
    *(reinterpret_cast<float4*>(outB + (size_t)node * FDIM) + lane) = o;
}

__global__ __launch_bounds__(256) void agg_norm_kernel(const unsigned short* __restrict__ hb,
                                                       const int* __restrict__ rowp,
                                                       const int2* __restrict__ edata,
                                                       const float* __restrict__ dinv,
                                                       const float* __restrict__ bias,
                                                       float* __restrict__ out, int n) {
    int node = (blockIdx.x * blockDim.x + threadIdx.x) >> 6;
    int lane = threadIdx.x & 63;
    if (node >= n) return;
    float a0, a1, a2, a3;
    agg_core(hb, rowp, edata, dinv, bias, node, lane, a0, a1, a2, a3);
    float ss = a0 * a0 + a1 * a1 + a2 * a2 + a3 * a3;
#pragma unroll
    for (int off = 32; off >= 1; off >>= 1) ss += __shfl_xor(ss, off, 64);
    float rinv = 1.f / fmaxf(sqrtf(ss), 1e-12f);
    float4 o = make_float4(a0 * rinv, a1 * rinv, a2 * rinv, a3 * rinv);
    *(reinterpret_cast<float4*>(out + (size_t)node * FDIM) + lane) = o;
}

extern "C" void kernel_launch(void* const* d_in, const int* in_sizes, int n_in,
                              void* d_out, int out_size, void* d_ws, size_t ws_size,
                              hipStream_t stream) {
    const float* x  = (const float*)d_in[0];
    const int*   ei = (const int*)d_in[1];
    const float* W1 = (const float*)d_in[2];
    const float* b1 = (const float*)d_in[3];
    const float* W2 = (const float*)d_in[4];
    const float* b2 = (const float*)d_in[5];
    float* out = (float*)d_out;

    const int N = NNODE;
    const int E = in_sizes[1] / 2;
    const int NB = (N + SCAN_CHUNK - 1) / SCAN_CHUNK;

    char* ws = (char*)d_ws;
    size_t off = 0;
    auto alloc = [&](size_t bytes) -> void* {
        void* p = ws + off;
        off = (off + bytes + 255) & ~(size_t)255;
        return p;
    };
    unsigned short* Hbf = (unsigned short*)alloc((size_t)N * FDIM * 2);  // h1 then h2 (bf16)
    float* B      = (float*)alloc((size_t)N * FDIM * 4);                 // relu(gcn1) fp32
    int*   counts = (int*)alloc((size_t)N * 4);
    int*   rowp   = (int*)alloc((size_t)(N + 1) * 4);
    int*   cursor = (int*)alloc((size_t)N * 4);
    float* dinv   = (float*)alloc((size_t)N * 4);
    int2*  edata  = (int2*)alloc((size_t)E * 8);
    int*   bsum   = (int*)alloc((size_t)NB * 4);
    int*   boff   = (int*)alloc((size_t)NB * 4);

    hipMemsetAsync(counts, 0, (size_t)N * 4, stream);
    count_kernel<<<(E + 255) / 256, 256, 0, stream>>>(ei, counts, E);
    scan_part1<<<NB, 256, 0, stream>>>(counts, bsum, N);
    scan_part2<<<1, 64, 0, stream>>>(bsum, boff, rowp, NB, N);
    scan_part3<<<NB, 256, 0, stream>>>(counts, boff, rowp, cursor, N);
    dinv_kernel<<<(N + 255) / 256, 256, 0, stream>>>(counts, dinv, N);
    fill_kernel<<<(E + 255) / 256, 256, 0, stream>>>(ei, dinv, cursor, edata, E);

    gemm16<128><<<(N + 15) / 16, 256, 0, stream>>>(x, W1, Hbf, N);
    agg_relu_kernel<<<(N * 64 + 255) / 256, 256, 0, stream>>>(Hbf, rowp, edata, dinv, b1, B, N);
    gemm16<256><<<(N + 15) / 16, 256, 0, stream>>>(B, W2, Hbf, N);
    agg_norm_kernel<<<(N * 64 + 255) / 256, 256, 0, stream>>>(Hbf, rowp, edata, dinv, b2, out, N);
}

// Round 3
// 254.098 us; speedup vs baseline: 2.7313x; 1.5804x over previous
//
#include <hip/hip_runtime.h>
#include <hip/hip_bf16.h>

// GCN encoder: 2x GCNConv (sym-norm, self-loops) + ReLU + row L2 normalize.
// N=50000, E=800000, IN=128, HID=256, OUT=256.
// MFMA bf16 GEMMs (fp32 accum), bf16 gather payload, fp32 edge math.

#define NNODE 50000
#define FDIM 256
#define SCAN_CHUNK 2048

typedef __attribute__((ext_vector_type(8))) short short8;   // 8 bf16 (4 VGPRs)
typedef __attribute__((ext_vector_type(4))) float f32x4;    // MFMA acc

__device__ __forceinline__ float bf2f(unsigned short u) {
    union { unsigned int i; float f; } c;
    c.i = ((unsigned int)u) << 16;
    return c.f;
}
__device__ __forceinline__ unsigned short f2bf(float f) {
    __hip_bfloat16 h = __float2bfloat16(f);  // RTN
    return *reinterpret_cast<unsigned short*>(&h);
}

// ---- CSR build ----------------------------------------------------------
__global__ void count_kernel(const int* __restrict__ ei, int* __restrict__ counts, int E) {
    int e = blockIdx.x * blockDim.x + threadIdx.x;
    if (e < E) atomicAdd(&counts[ei[E + e]], 1);
}

__global__ __launch_bounds__(256) void scan_part1(const int* __restrict__ counts,
                                                  int* __restrict__ bsum, int n) {
    __shared__ int ws[4];
    int b = blockIdx.x, t = threadIdx.x;
    int base = b * SCAN_CHUNK + t * 8;
    int s = 0;
#pragma unroll
    for (int j = 0; j < 8; ++j) {
        int i = base + j;
        if (i < n) s += counts[i];
    }
#pragma unroll
    for (int off = 32; off >= 1; off >>= 1) s += __shfl_xor(s, off, 64);
    if ((t & 63) == 0) ws[t >> 6] = s;
    __syncthreads();
    if (t == 0) bsum[b] = ws[0] + ws[1] + ws[2] + ws[3];
}

__global__ void scan_part2(const int* __restrict__ bsum, int* __restrict__ boff,
                           int* __restrict__ row_ptr, int nb, int n) {
    int l = threadIdx.x;
    int v = (l < nb) ? bsum[l] : 0;
    int incl = v;
#pragma unroll
    for (int off = 1; off < 64; off <<= 1) {
        int u = __shfl_up(incl, off, 64);
        if (l >= off) incl += u;
    }
    if (l < nb) boff[l] = incl - v;
    if (l == nb - 1) row_ptr[n] = incl;  // total == E
}

__global__ __launch_bounds__(256) void scan_part3(const int* __restrict__ counts,
                                                  const int* __restrict__ boff,
                                                  int* __restrict__ row_ptr,
                                                  int* __restrict__ cursor, int n) {
    __shared__ int ws[4];
    int b = blockIdx.x, t = threadIdx.x, lane = t & 63, wid = t >> 6;
    int base = b * SCAN_CHUNK + t * 8;
    int v[8];
    int s = 0;
#pragma unroll
    for (int j = 0; j < 8; ++j) {
        int i = base + j;
        v[j] = (i < n) ? counts[i] : 0;
        s += v[j];
    }
    int incl = s;
#pragma unroll
    for (int off = 1; off < 64; off <<= 1) {
        int u = __shfl_up(incl, off, 64);
        if (lane >= off) incl += u;
    }
    if (lane == 63) ws[wid] = incl;
    __syncthreads();
    int woff = 0;
    for (int u = 0; u < wid; ++u) woff += ws[u];
    int ex = boff[b] + woff + incl - s;
#pragma unroll
    for (int j = 0; j < 8; ++j) {
        int i = base + j;
        if (i < n) { row_ptr[i] = ex; cursor[i] = ex; }
        ex += v[j];
    }
}

__global__ void dinv_kernel(const int* __restrict__ counts, float* __restrict__ dinv, int n) {
    int i = blockIdx.x * blockDim.x + threadIdx.x;
    if (i < n) dinv[i] = rsqrtf((float)(counts[i] + 1));  // +1 self-loop
}

__global__ void fill_kernel(const int* __restrict__ ei, const float* __restrict__ dinv,
                            int* __restrict__ cursor, int2* __restrict__ edata, int E) {
    int e = blockIdx.x * blockDim.x + threadIdx.x;
    if (e < E) {
        int s = ei[e];
        int d = ei[E + e];
        int pos = atomicAdd(&cursor[d], 1);
        float nm = dinv[s] * dinv[d];
        edata[pos] = make_int2(s, __float_as_int(nm));
    }
}

// ---- W repack: Wf[g][col][j] = bf16(W[8g+j][col]), fragment-ready -------
template <int K>
__global__ void wconv_kernel(const float* __restrict__ W, unsigned short* __restrict__ Wf) {
    int idx = blockIdx.x * blockDim.x + threadIdx.x;  // (g, col)
    if (idx >= (K / 8) * 256) return;
    int g = idx >> 8, c = idx & 255;
    ushort4 lo = make_ushort4(f2bf(W[(8 * g + 0) * 256 + c]), f2bf(W[(8 * g + 1) * 256 + c]),
                              f2bf(W[(8 * g + 2) * 256 + c]), f2bf(W[(8 * g + 3) * 256 + c]));
    ushort4 hi = make_ushort4(f2bf(W[(8 * g + 4) * 256 + c]), f2bf(W[(8 * g + 5) * 256 + c]),
                              f2bf(W[(8 * g + 6) * 256 + c]), f2bf(W[(8 * g + 7) * 256 + c]));
    *reinterpret_cast<ushort4*>(&Wf[(size_t)idx * 8]) = lo;
    *reinterpret_cast<ushort4*>(&Wf[(size_t)idx * 8 + 4]) = hi;
}

// ---- MFMA GEMM: H[n,256] = bf16(X[n,K] @ W[K,256]) ----------------------
// 4 waves/block, BM=32. Wave w: rows[0,32) x cols[64w,64w+64).
// LDS A layout: As[g=k/8][row^(g&7)][8] -> 16B frags, conflict-free reads.
template <int K, typename T>
__global__ __launch_bounds__(256) void gemm_mfma(const T* __restrict__ X,
                                                 const unsigned short* __restrict__ Wf,
                                                 unsigned short* __restrict__ H, int n) {
    __shared__ unsigned short As[(K / 8) * 32 * 8];
    int t = threadIdx.x;
    int row0 = blockIdx.x * 32;

    if constexpr (sizeof(T) == 4) {  // fp32 input -> convert while staging
#pragma unroll
        for (int i = 0; i < K / 32; ++i) {
            int o = 4 * (t + 256 * i);
            int row = o / K, k = o % K;
            int srow = row0 + row;
            float4 v = make_float4(0.f, 0.f, 0.f, 0.f);
            if (srow < n) v = *reinterpret_cast<const float4*>(&X[(size_t)srow * K + k]);
            ushort4 p = make_ushort4(f2bf(v.x), f2bf(v.y), f2bf(v.z), f2bf(v.w));
            int g = k >> 3;
            int idx = g * 32 + (row ^ (g & 7));
            *reinterpret_cast<ushort4*>(&As[idx * 8 + (k & 7)]) = p;
        }
    } else {  // bf16 input -> straight copy
#pragma unroll
        for (int i = 0; i < K / 64; ++i) {
            int o = 8 * (t + 256 * i);
            int row = o / K, k = o % K;
            int srow = row0 + row;
            uint4 v = make_uint4(0u, 0u, 0u, 0u);
            if (srow < n) v = *reinterpret_cast<const uint4*>(&X[(size_t)srow * K + k]);
            int g = k >> 3;
            int idx = g * 32 + (row ^ (g & 7));
            *reinterpret_cast<uint4*>(&As[idx * 8]) = v;
        }
    }
    __syncthreads();

    int lane = t & 63, wv = t >> 6;
    int l15 = lane & 15, lhi = lane >> 4;
    f32x4 zero = {0.f, 0.f, 0.f, 0.f};
    f32x4 acc[2][4];
#pragma unroll
    for (int rf = 0; rf < 2; ++rf)
#pragma unroll
        for (int cf = 0; cf < 4; ++cf) acc[rf][cf] = zero;

#pragma unroll
    for (int s = 0; s < K / 32; ++s) {
        int g = 4 * s + lhi;
        int g7 = g & 7;
        short8 a0 = *reinterpret_cast<const short8*>(&As[(g * 32 + (l15 ^ g7)) * 8]);
        short8 a1 = *reinterpret_cast<const short8*>(&As[(g * 32 + ((16 + l15) ^ g7)) * 8]);
#pragma unroll
        for (int cf = 0; cf < 4; ++cf) {
            int col = 64 * wv + 16 * cf + l15;
            short8 b = *reinterpret_cast<const short8*>(&Wf[((size_t)g * 256 + col) * 8]);
            acc[0][cf] = __builtin_amdgcn_mfma_f32_16x16x32_bf16(a0, b, acc[0][cf], 0, 0, 0);
            acc[1][cf] = __builtin_amdgcn_mfma_f32_16x16x32_bf16(a1, b, acc[1][cf], 0, 0, 0);
        }
    }

#pragma unroll
    for (int rf = 0; rf < 2; ++rf)
#pragma unroll
        for (int cf = 0; cf < 4; ++cf) {
            f32x4 a = acc[rf][cf];
            int colb = 64 * wv + 16 * cf + l15;
#pragma unroll
            for (int j = 0; j < 4; ++j) {
                int row = row0 + 16 * rf + lhi * 4 + j;
                if (row < n) H[(size_t)row * 256 + colb] = f2bf(a[j]);
            }
        }
}

// ---- Aggregation, wave-per-node. Lane l owns features [4l, 4l+4). -------
__device__ __forceinline__ void agg_core(const unsigned short* __restrict__ hb,
                                         const int* __restrict__ rowp,
                                         const int2* __restrict__ edata,
                                         const float* __restrict__ dinv,
                                         const float* __restrict__ bias,
                                         int node, int lane,
                                         float& a0, float& a1, float& a2, float& a3) {
    float di = dinv[node];
    float d2 = di * di;
    ushort4 sv = *(reinterpret_cast<const ushort4*>(hb + (size_t)node * FDIM) + lane);
    float4 bv = *(reinterpret_cast<const float4*>(bias) + lane);
    a0 = fmaf(bf2f(sv.x), d2, bv.x);
    a1 = fmaf(bf2f(sv.y), d2, bv.y);
    a2 = fmaf(bf2f(sv.z), d2, bv.z);
    a3 = fmaf(bf2f(sv.w), d2, bv.w);
    int beg = rowp[node], end = rowp[node + 1];
#pragma unroll 4
    for (int e = beg; e < end; ++e) {
        int2 ed = edata[e];
        float nm = __int_as_float(ed.y);
        ushort4 v = *(reinterpret_cast<const ushort4*>(hb + (size_t)ed.x * FDIM) + lane);
        a0 = fmaf(bf2f(v.x), nm, a0);
        a1 = fmaf(bf2f(v.y), nm, a1);
        a2 = fmaf(bf2f(v.z), nm, a2);
        a3 = fmaf(bf2f(v.w), nm, a3);
    }
}

__global__ __launch_bounds__(256) void agg_relu_kernel(const unsigned short* __restrict__ hb,
                                                       const int* __restrict__ rowp,
                                                       const int2* __restrict__ edata,
                                                       const float* __restrict__ dinv,
                                                       const float* __restrict__ bias,
                                                       unsigned short* __restrict__ outB, int n) {
    int node = (blockIdx.x * blockDim.x + threadIdx.x) >> 6;
    int lane = threadIdx.x & 63;
    if (node >= n) return;
    float a0, a1, a2, a3;
    agg_core(hb, rowp, edata, dinv, bias, node, lane, a0, a1, a2, a3);
    ushort4 o = make_ushort4(f2bf(fmaxf(a0, 0.f)), f2bf(fmaxf(a1, 0.f)),
                             f2bf(fmaxf(a2, 0.f)), f2bf(fmaxf(a3, 0.f)));
    *(reinterpret_cast<ushort4*>(outB + (size_t)node * FDIM) + lane) = o;
}

__global__ __launch_bounds__(256) void agg_norm_kernel(const unsigned short* __restrict__ hb,
                                                       const int* __restrict__ rowp,
                                                       const int2* __restrict__ edata,
                                                       const float* __restrict__ dinv,
                                                       const float* __restrict__ bias,
                                                       float* __restrict__ out, int n) {
    int node = (blockIdx.x * blockDim.x + threadIdx.x) >> 6;
    int lane = threadIdx.x & 63;
    if (node >= n) return;
    float a0, a1, a2, a3;
    agg_core(hb, rowp, edata, dinv, bias, node, lane, a0, a1, a2, a3);
    float ss = a0 * a0 + a1 * a1 + a2 * a2 + a3 * a3;
#pragma unroll
    for (int off = 32; off >= 1; off >>= 1) ss += __shfl_xor(ss, off, 64);
    float rinv = 1.f / fmaxf(sqrtf(ss), 1e-12f);
    float4 o = make_float4(a0 * rinv, a1 * rinv, a2 * rinv, a3 * rinv);
    *(reinterpret_cast<float4*>(out + (size_t)node * FDIM) + lane) = o;
}

extern "C" void kernel_launch(void* const* d_in, const int* in_sizes, int n_in,
                              void* d_out, int out_size, void* d_ws, size_t ws_size,
                              hipStream_t stream) {
    const float* x  = (const float*)d_in[0];
    const int*   ei = (const int*)d_in[1];
    const float* W1 = (const float*)d_in[2];
    const float* b1 = (const float*)d_in[3];
    const float* W2 = (const float*)d_in[4];
    const float* b2 = (const float*)d_in[5];
    float* out = (float*)d_out;

    const int N = NNODE;
    const int E = in_sizes[1] / 2;
    const int NB = (N + SCAN_CHUNK - 1) / SCAN_CHUNK;

    char* ws = (char*)d_ws;
    size_t off = 0;
    auto alloc = [&](size_t bytes) -> void* {
        void* p = ws + off;
        off = (off + bytes + 255) & ~(size_t)255;
        return p;
    };
    unsigned short* Hbf = (unsigned short*)alloc((size_t)N * FDIM * 2);  // h1 then h2
    unsigned short* Bbf = (unsigned short*)alloc((size_t)N * FDIM * 2);  // relu(gcn1)
    unsigned short* Wf1 = (unsigned short*)alloc((size_t)(128 / 8) * 256 * 8 * 2);
    unsigned short* Wf2 = (unsigned short*)alloc((size_t)(256 / 8) * 256 * 8 * 2);
    int*   counts = (int*)alloc((size_t)N * 4);
    int*   rowp   = (int*)alloc((size_t)(N + 1) * 4);
    int*   cursor = (int*)alloc((size_t)N * 4);
    float* dinv   = (float*)alloc((size_t)N * 4);
    int2*  edata  = (int2*)alloc((size_t)E * 8);
    int*   bsum   = (int*)alloc((size_t)NB * 4);
    int*   boff   = (int*)alloc((size_t)NB * 4);

    wconv_kernel<128><<<(16 * 256 + 255) / 256, 256, 0, stream>>>(W1, Wf1);
    wconv_kernel<256><<<(32 * 256 + 255) / 256, 256, 0, stream>>>(W2, Wf2);

    hipMemsetAsync(counts, 0, (size_t)N * 4, stream);
    count_kernel<<<(E + 255) / 256, 256, 0, stream>>>(ei, counts, E);
    scan_part1<<<NB, 256, 0, stream>>>(counts, bsum, N);
    scan_part2<<<1, 64, 0, stream>>>(bsum, boff, rowp, NB, N);
    scan_part3<<<NB, 256, 0, stream>>>(counts, boff, rowp, cursor, N);
    dinv_kernel<<<(N + 255) / 256, 256, 0, stream>>>(counts, dinv, N);
    fill_kernel<<<(E + 255) / 256, 256, 0, stream>>>(ei, dinv, cursor, edata, E);

    gemm_mfma<128, float><<<(N + 31) / 32, 256, 0, stream>>>(x, Wf1, Hbf, N);
    agg_relu_kernel<<<(N * 64 + 255) / 256, 256, 0, stream>>>(Hbf, rowp, edata, dinv, b1, Bbf, N);
    gemm_mfma<256, unsigned short><<<(N + 31) / 32, 256, 0, stream>>>(Bbf, Wf2, Hbf, N);
    agg_norm_kernel<<<(N * 64 + 255) / 256, 256, 0, stream>>>(Hbf, rowp, edata, dinv, b2, out, N);
}